// Round 8
// baseline (638.012 us; speedup 1.0000x reference)
//
#include <hip/hip_runtime.h>
#include <stdint.h>

#define F_IN 512
#define HF 256
#define OUT_F 2
#define BN_EPS 1e-5f
#define SCAN_B 256
#define LDSTR 36   // LDS row stride in shorts (72 B) -> 0 bank conflicts (measured R7)

typedef __attribute__((ext_vector_type(8))) short bf16x8;
typedef __attribute__((ext_vector_type(4))) float f32x4;

__device__ inline float bf2f(unsigned short u) {
    union { float f; uint32_t i; } v; v.i = ((uint32_t)u) << 16; return v.f;
}
__device__ inline unsigned short f2bf(float f) {
    union { float f; uint32_t i; } v; v.f = f;
    uint32_t r = v.i + 0x7FFFu + ((v.i >> 16) & 1u);   // RNE (finite values only)
    return (unsigned short)(r >> 16);
}

// ---------- prep: packed deg/count init + W1/W2 transpose-to-bf16 ----------
__global__ void prep_kernel(unsigned long long* __restrict__ packed,
                            const float* __restrict__ W1, unsigned short* __restrict__ W1t,
                            const float* __restrict__ W2, unsigned short* __restrict__ W2t,
                            int n) {
    int idx = blockIdx.x * blockDim.x + threadIdx.x;
    if (idx < n) { packed[idx] = 1ULL << 20; return; }   // self-loop w=1.0 in 24.20 fixpoint
    int j = idx - n;
    if (j < F_IN * HF) {                       // W1t[nn*F_IN + k] = bf16(W1[k*HF + nn])
        int nn = j >> 9, k = j & (F_IN - 1);
        W1t[j] = f2bf(W1[(size_t)k * HF + nn]);
        return;
    }
    j -= F_IN * HF;
    if (j < HF * HF) {                         // W2t[nn*HF + k] = bf16(W2[k*HF + nn])
        int nn = j >> 8, k = j & (HF - 1);
        W2t[j] = f2bf(W2[(size_t)k * HF + nn]);
    }
}

// ---------- wide GEMM body: C[64 x 256](bf16) per block = A[64,K] @ Bt[256,K]^T ----------
// BM=64, BN=256 (full width -> A read exactly once), BK=32.
// 4 waves; wave wv: rows wv*16..+16, all 256 cols (16 MFMA 16x16x32 tiles, 1 A-frag).
template<int A_IS_F32>
__device__ __forceinline__
void gemm_body(const void* __restrict__ Araw, const unsigned short* __restrict__ Bt,
               unsigned short* __restrict__ C, int Mvalid, int K, int mblk,
               unsigned short* As, unsigned short* Bs) {
    const int tid  = threadIdx.x;
    const int lane = tid & 63;
    const int wv   = tid >> 6;
    const int m0 = mblk * 64;

    const int sr = tid >> 2;          // staging row 0..63
    const int sc = (tid & 3) * 8;     // staging k-offset 0,8,16,24

    f32x4 zero4 = {0.0f, 0.0f, 0.0f, 0.0f};
    f32x4 acc[16];
    #pragma unroll
    for (int j = 0; j < 16; ++j) acc[j] = zero4;

    const int q8 = (lane >> 4) * 8;
    const int ml = lane & 15;

    for (int k0 = 0; k0 < K; k0 += 32) {
        // ---- stage A tile (64 x 32) ----
        if (A_IS_F32) {
            const float* A = (const float*)Araw;
            int gm = m0 + sr;
            float4 f0 = {0.f, 0.f, 0.f, 0.f}, f1 = {0.f, 0.f, 0.f, 0.f};
            if (gm < Mvalid) {
                f0 = *(const float4*)(A + (size_t)gm * K + k0 + sc);
                f1 = *(const float4*)(A + (size_t)gm * K + k0 + sc + 4);
            }
            bf16x8 v;
            v[0] = (short)f2bf(f0.x); v[1] = (short)f2bf(f0.y);
            v[2] = (short)f2bf(f0.z); v[3] = (short)f2bf(f0.w);
            v[4] = (short)f2bf(f1.x); v[5] = (short)f2bf(f1.y);
            v[6] = (short)f2bf(f1.z); v[7] = (short)f2bf(f1.w);
            *(bf16x8*)&As[sr * LDSTR + sc] = v;
        } else {
            const unsigned short* A = (const unsigned short*)Araw;
            int gm = m0 + sr;
            bf16x8 v = {0, 0, 0, 0, 0, 0, 0, 0};
            if (gm < Mvalid) v = *(const bf16x8*)(A + (size_t)gm * K + k0 + sc);
            *(bf16x8*)&As[sr * LDSTR + sc] = v;
        }
        // ---- stage B tile (256 n x 32 k); B is L2-resident (<=256 KB) ----
        #pragma unroll
        for (int h = 0; h < 4; ++h) {
            int rr = sr + h * 64;
            bf16x8 v = *(const bf16x8*)(Bt + (size_t)rr * K + k0 + sc);
            *(bf16x8*)&Bs[rr * LDSTR + sc] = v;
        }
        __syncthreads();

        bf16x8 af = *(const bf16x8*)&As[(wv * 16 + ml) * LDSTR + q8];
        #pragma unroll
        for (int j = 0; j < 16; ++j) {
            bf16x8 bfr = *(const bf16x8*)&Bs[(j * 16 + ml) * LDSTR + q8];
            acc[j] = __builtin_amdgcn_mfma_f32_16x16x32_bf16(af, bfr, acc[j], 0, 0, 0);
        }
        __syncthreads();
    }

    // C store (bf16): col=lane&15, row=(lane>>4)*4+reg
    const int q4 = (lane >> 4) * 4;
    #pragma unroll
    for (int j = 0; j < 16; ++j) {
        #pragma unroll
        for (int rg = 0; rg < 4; ++rg) {
            int r = m0 + wv * 16 + q4 + rg;
            int c = j * 16 + ml;
            C[(size_t)r * HF + c] = f2bf(acc[j][rg]);
        }
    }
}

// ---------- fused: packed deg/count atomics (blocks < ncount, run FIRST) + GEMM1 ----------
__global__ __launch_bounds__(256)
void gemm1_count_kernel(const float* __restrict__ x, const unsigned short* __restrict__ W1t,
                        unsigned short* __restrict__ C,
                        const int* __restrict__ col, const float* __restrict__ w,
                        unsigned long long* __restrict__ packed,
                        int Mvalid, int e, int ncount) {
    __shared__ unsigned short As[64 * LDSTR];
    __shared__ unsigned short Bs[256 * LDSTR];
    int bid = blockIdx.x;
    if (bid < ncount) {
        int base = bid * 1024 + (int)threadIdx.x;
        #pragma unroll
        for (int k = 0; k < 4; ++k) {
            int i = base + k * 256;
            if (i < e) {
                unsigned long long add = (1ULL << 40)
                    | (unsigned long long)__float2uint_rn(w[i] * 1048576.0f);
                atomicAdd(&packed[col[i]], add);
            }
        }
    } else {
        gemm_body<1>(x, W1t, C, Mvalid, F_IN, bid - ncount, As, Bs);
    }
}

// ---------- standalone GEMM (layer 2), bf16 A ----------
__global__ __launch_bounds__(256)
void gemm2_kernel(const unsigned short* __restrict__ A, const unsigned short* __restrict__ Bt,
                  unsigned short* __restrict__ C, int Mvalid) {
    __shared__ unsigned short As[64 * LDSTR];
    __shared__ unsigned short Bs[256 * LDSTR];
    gemm_body<0>(A, Bt, C, Mvalid, HF, blockIdx.x, As, Bs);
}

// ---------- scan1: block-local exclusive scan of counts ----------
__global__ void scan1_kernel(const unsigned long long* __restrict__ packed,
                             int* __restrict__ local, int* __restrict__ blocksum, int n) {
    __shared__ int tmp[SCAN_B];
    int i = blockIdx.x * SCAN_B + threadIdx.x;
    int v = (i < n) ? (int)(packed[i] >> 40) : 0;
    tmp[threadIdx.x] = v;
    __syncthreads();
    for (int off = 1; off < SCAN_B; off <<= 1) {
        int t = 0;
        if ((int)threadIdx.x >= off) t = tmp[threadIdx.x - off];
        __syncthreads();
        if ((int)threadIdx.x >= off) tmp[threadIdx.x] += t;
        __syncthreads();
    }
    if (i < n) local[i] = tmp[threadIdx.x] - v;       // exclusive
    if (threadIdx.x == SCAN_B - 1) blocksum[blockIdx.x] = tmp[SCAN_B - 1];
}

// ---------- scan3: add block prefix (re-reduced in-block) + dinv ----------
__global__ void scan3_dinv_kernel(int* __restrict__ csr_ptr, int* __restrict__ cursor,
                                  const int* __restrict__ blocksum,
                                  const unsigned long long* __restrict__ packed,
                                  float* __restrict__ dinv, int n, int e, int nb) {
    __shared__ int red[SCAN_B];
    int t = threadIdx.x;
    red[t] = (t < nb && t < (int)blockIdx.x) ? blocksum[t] : 0;
    __syncthreads();
    for (int off = SCAN_B / 2; off > 0; off >>= 1) {
        if (t < off) red[t] += red[t + off];
        __syncthreads();
    }
    int prefix = red[0];
    int i = blockIdx.x * SCAN_B + t;
    if (i < n) {
        int val = csr_ptr[i] + prefix;
        csr_ptr[i] = val;
        cursor[i] = val;
        float deg = (float)(packed[i] & 0xFFFFFFFFFFULL) * (1.0f / 1048576.0f);
        dinv[i] = rsqrtf(deg);   // deg >= 1 always (self-loop)
    }
    if (i == 0) csr_ptr[n] = e;
}

// ---------- CSR fill: bucket edges by col, fold norm, 8B paired store ----------
__global__ void fill_kernel(const int* __restrict__ row, const int* __restrict__ col,
                            const float* __restrict__ w, const float* __restrict__ dinv,
                            int* __restrict__ cursor, int2* __restrict__ csr_edge, int e) {
    int i = blockIdx.x * blockDim.x + threadIdx.x;
    if (i < e) {
        int r = row[i], c = col[i];
        int pos = atomicAdd(&cursor[c], 1);
        float nrm = dinv[r] * w[i] * dinv[c];
        csr_edge[pos] = make_int2(r, __float_as_int(nrm));
    }
}

// ---------- fused CSR gather + self-loop + bias + BN + ReLU ----------
// one wave per node; unconditional batches of 8, clamped masked tail.
// FINAL=1: additionally computes h3[node,2] = act . W3 (wave reduce), skips bf16 store.
template<int FINAL>
__global__ void agg_kernel(const unsigned short* __restrict__ h,
                           const int* __restrict__ ptr,
                           const int2* __restrict__ edge,
                           const float* __restrict__ dinv,
                           const float* __restrict__ b, const float* __restrict__ g,
                           const float* __restrict__ be, const float* __restrict__ m,
                           const float* __restrict__ v,
                           unsigned short* __restrict__ out,
                           const float* __restrict__ W3, float* __restrict__ h3, int n) {
    int wid  = (blockIdx.x * blockDim.x + threadIdx.x) >> 6;
    int lane = threadIdx.x & 63;
    if (wid >= n) return;
    int p0 = ptr[wid], p1 = ptr[wid + 1];
    const int fo = lane * 4;
    float a0 = 0.f, a1 = 0.f, a2 = 0.f, a3 = 0.f;

    const int pend = p0 + ((p1 - p0) & ~7);
    for (int p = p0; p < pend; p += 8) {
        int2 ed[8];
        #pragma unroll
        for (int k = 0; k < 8; ++k) ed[k] = edge[p + k];
        ushort4 hv[8];
        #pragma unroll
        for (int k = 0; k < 8; ++k)
            hv[k] = *(const ushort4*)(h + (size_t)ed[k].x * HF + fo);
        #pragma unroll
        for (int k = 0; k < 8; ++k) {
            float nw = __int_as_float(ed[k].y);
            a0 += nw * bf2f(hv[k].x);
            a1 += nw * bf2f(hv[k].y);
            a2 += nw * bf2f(hv[k].z);
            a3 += nw * bf2f(hv[k].w);
        }
    }
    if (pend < p1) {   // masked tail batch of 8
        int2 ed[8];
        float wv[8];
        #pragma unroll
        for (int k = 0; k < 8; ++k) {
            int idx = pend + k < p1 ? pend + k : p1 - 1;
            ed[k] = edge[idx];
            wv[k] = (pend + k < p1) ? __int_as_float(ed[k].y) : 0.0f;
        }
        ushort4 hv[8];
        #pragma unroll
        for (int k = 0; k < 8; ++k)
            hv[k] = *(const ushort4*)(h + (size_t)ed[k].x * HF + fo);
        #pragma unroll
        for (int k = 0; k < 8; ++k) {
            a0 += wv[k] * bf2f(hv[k].x);
            a1 += wv[k] * bf2f(hv[k].y);
            a2 += wv[k] * bf2f(hv[k].z);
            a3 += wv[k] * bf2f(hv[k].w);
        }
    }
    // self loop: weight 1, norm = dinv^2
    float s = dinv[wid];
    float sl = s * s;
    ushort4 hv = *(const ushort4*)(h + (size_t)wid * HF + fo);
    a0 += sl * bf2f(hv.x);
    a1 += sl * bf2f(hv.y);
    a2 += sl * bf2f(hv.z);
    a3 += sl * bf2f(hv.w);

    float4 bb  = *(const float4*)(b + fo);
    float4 gg  = *(const float4*)(g + fo);
    float4 bee = *(const float4*)(be + fo);
    float4 mm  = *(const float4*)(m + fo);
    float4 vv  = *(const float4*)(v + fo);
    float f0 = fmaxf((a0 + bb.x - mm.x) * rsqrtf(vv.x + BN_EPS) * gg.x + bee.x, 0.f);
    float f1 = fmaxf((a1 + bb.y - mm.y) * rsqrtf(vv.y + BN_EPS) * gg.y + bee.y, 0.f);
    float f2 = fmaxf((a2 + bb.z - mm.z) * rsqrtf(vv.z + BN_EPS) * gg.z + bee.z, 0.f);
    float f3 = fmaxf((a3 + bb.w - mm.w) * rsqrtf(vv.w + BN_EPS) * gg.w + bee.w, 0.f);

    if (!FINAL) {
        ushort4 o;
        o.x = f2bf(f0); o.y = f2bf(f1); o.z = f2bf(f2); o.w = f2bf(f3);
        *(ushort4*)(out + (size_t)wid * HF + fo) = o;
    } else {
        // fused layer-3 GEMV: h3[wid, o] = sum_f act[f] * W3[f][o]
        float4 w0 = *(const float4*)(W3 + fo * 2);
        float4 w1 = *(const float4*)(W3 + fo * 2 + 4);
        float s0 = f0 * w0.x + f1 * w0.z + f2 * w1.x + f3 * w1.z;
        float s1 = f0 * w0.y + f1 * w0.w + f2 * w1.y + f3 * w1.w;
        #pragma unroll
        for (int o = 32; o > 0; o >>= 1) {
            s0 += __shfl_down(s0, o, 64);
            s1 += __shfl_down(s1, o, 64);
        }
        if (lane == 0) {
            h3[wid * 2 + 0] = s0;
            h3[wid * 2 + 1] = s1;
        }
    }
}

// ---------- final: CSR gather (2 features) + self-loop + bias ----------
__global__ void out_kernel(const float* __restrict__ h3,
                           const int* __restrict__ ptr, const int2* __restrict__ edge,
                           const float* __restrict__ dinv,
                           const float* __restrict__ b3, float* __restrict__ out, int n) {
    int i = blockIdx.x * blockDim.x + threadIdx.x;
    if (i >= n) return;
    int p0 = ptr[i], p1 = ptr[i + 1];
    float a0 = 0.f, a1 = 0.f;
    for (int p = p0; p < p1; p += 4) {
        #pragma unroll
        for (int k = 0; k < 4; ++k) {
            int idx = p + k < p1 ? p + k : p1 - 1;
            int2 e = edge[idx];
            float nw = (p + k < p1) ? __int_as_float(e.y) : 0.0f;
            float2 u = *(const float2*)(h3 + 2 * e.x);
            a0 += nw * u.x;
            a1 += nw * u.y;
        }
    }
    float s = dinv[i];
    float sl = s * s;
    out[2 * i + 0] = a0 + sl * h3[2 * i + 0] + b3[0];
    out[2 * i + 1] = a1 + sl * h3[2 * i + 1] + b3[1];
}

static inline char* align16(char* p) {
    return (char*)(((uintptr_t)p + 15) & ~(uintptr_t)15);
}

extern "C" void kernel_launch(void* const* d_in, const int* in_sizes, int n_in,
                              void* d_out, int out_size, void* d_ws, size_t ws_size,
                              hipStream_t stream) {
    const float* x   = (const float*)d_in[0];
    const int*   ei  = (const int*)d_in[1];    // int64 in reference -> int32 in harness
    const float* ew  = (const float*)d_in[2];
    const float* W1  = (const float*)d_in[3];
    const float* b1  = (const float*)d_in[4];
    const float* g1  = (const float*)d_in[5];
    const float* be1 = (const float*)d_in[6];
    const float* m1  = (const float*)d_in[7];
    const float* v1  = (const float*)d_in[8];
    const float* W2  = (const float*)d_in[9];
    const float* b2  = (const float*)d_in[10];
    const float* g2  = (const float*)d_in[11];
    const float* be2 = (const float*)d_in[12];
    const float* m2  = (const float*)d_in[13];
    const float* v2  = (const float*)d_in[14];
    const float* W3  = (const float*)d_in[15];
    const float* b3  = (const float*)d_in[16];

    const int N  = in_sizes[0] / F_IN;         // 50000
    const int E  = in_sizes[2];                // 800000
    const int MP = (N + 63) & ~63;             // 50048 (multiple of 64)
    const int* row = ei;
    const int* col = ei + E;

    char* wsb = (char*)d_ws;
    unsigned long long* packed = (unsigned long long*)wsb; wsb = align16(wsb + (size_t)N * 8);
    float* dinv     = (float*)wsb;          wsb = align16(wsb + (size_t)N * 4);
    int*   csr_ptr  = (int*)wsb;            wsb = align16(wsb + (size_t)(N + 1) * 4);
    int*   cursor   = (int*)wsb;            wsb = align16(wsb + (size_t)N * 4);
    int*   blocksum = (int*)wsb;            wsb = align16(wsb + (size_t)SCAN_B * 4);
    int2*  csr_edge = (int2*)wsb;           wsb = align16(wsb + (size_t)E * 8);
    unsigned short* W1t = (unsigned short*)wsb;  wsb = align16(wsb + (size_t)F_IN * HF * 2);
    unsigned short* W2t = (unsigned short*)wsb;  wsb = align16(wsb + (size_t)HF * HF * 2);
    unsigned short* bufh = (unsigned short*)wsb; wsb = align16(wsb + (size_t)MP * HF * 2);
    unsigned short* bufa = (unsigned short*)wsb; wsb = align16(wsb + (size_t)MP * HF * 2);
    float* h3 = (float*)wsb;                wsb = align16(wsb + (size_t)N * OUT_F * 4);
    float* outf = (float*)d_out;

    const int TB = 256;
    const int nscan = (N + SCAN_B - 1) / SCAN_B;        // 196
    const int preptot = N + F_IN * HF + HF * HF;
    const int ngemm = MP / 64;                          // 782
    const int ncount = (E + 1023) / 1024;               // 782

    // --- prep: packed init + weight transposes ---
    prep_kernel<<<(preptot + TB - 1) / TB, TB, 0, stream>>>(packed, W1, W1t, W2, W2t, N);

    // --- fused: deg/count atomics FIRST (overlap), then GEMM1 blocks ---
    gemm1_count_kernel<<<ncount + ngemm, TB, 0, stream>>>(
        x, W1t, bufh, col, ew, packed, N, E, ncount);

    // --- CSR build ---
    scan1_kernel<<<nscan, SCAN_B, 0, stream>>>(packed, csr_ptr, blocksum, N);
    scan3_dinv_kernel<<<nscan, SCAN_B, 0, stream>>>(csr_ptr, cursor, blocksum, packed, dinv, N, E, nscan);
    fill_kernel<<<(E + TB - 1) / TB, TB, 0, stream>>>(row, col, ew, dinv, cursor, csr_edge, E);

    // --- layer 1 aggregation (+BN+ReLU) ---
    agg_kernel<0><<<((size_t)N * 64 + TB - 1) / TB, TB, 0, stream>>>(
        bufh, csr_ptr, csr_edge, dinv, b1, g1, be1, m1, v1, bufa, nullptr, nullptr, N);

    // --- layer 2 GEMM ---
    gemm2_kernel<<<ngemm, TB, 0, stream>>>(bufa, W2t, bufh, MP);

    // --- layer 2 aggregation (+BN+ReLU) fused with layer-3 GEMV ---
    agg_kernel<1><<<((size_t)N * 64 + TB - 1) / TB, TB, 0, stream>>>(
        bufh, csr_ptr, csr_edge, dinv, b2, g2, be2, m2, v2, nullptr, W3, h3, N);

    // --- final 2-feature aggregation ---
    out_kernel<<<(N + TB - 1) / TB, TB, 0, stream>>>(h3, csr_ptr, csr_edge, dinv, b3, outf, N);
}

// Round 9
// 534.852 us; speedup vs baseline: 1.1929x; 1.1929x over previous
//
#include <hip/hip_runtime.h>
#include <stdint.h>

#define F_IN 512
#define HF 256
#define OUT_F 2
#define BN_EPS 1e-5f
#define SCAN_B 256
#define LDSTR 36    // K-loop staging row stride (shorts): 0 conflicts (measured R7)
#define EPSTR 136   // epilogue row stride (shorts): 272 B = 16-B aligned

typedef __attribute__((ext_vector_type(8))) short bf16x8;
typedef __attribute__((ext_vector_type(4))) float f32x4;

__device__ inline float bf2f(unsigned short u) {
    union { float f; uint32_t i; } v; v.i = ((uint32_t)u) << 16; return v.f;
}
__device__ inline unsigned short f2bf(float f) {
    union { float f; uint32_t i; } v; v.f = f;
    uint32_t r = v.i + 0x7FFFu + ((v.i >> 16) & 1u);   // RNE (finite values only)
    return (unsigned short)(r >> 16);
}

// ---------- prep: packed deg/count init + W1/W2 transpose-to-bf16 ----------
__global__ void prep_kernel(unsigned long long* __restrict__ packed,
                            const float* __restrict__ W1, unsigned short* __restrict__ W1t,
                            const float* __restrict__ W2, unsigned short* __restrict__ W2t,
                            int n) {
    int idx = blockIdx.x * blockDim.x + threadIdx.x;
    if (idx < n) { packed[idx] = 1ULL << 20; return; }   // self-loop w=1.0 in 24.20 fixpoint
    int j = idx - n;
    if (j < F_IN * HF) {                       // W1t[nn*F_IN + k] = bf16(W1[k*HF + nn])
        int nn = j >> 9, k = j & (F_IN - 1);
        W1t[j] = f2bf(W1[(size_t)k * HF + nn]);
        return;
    }
    j -= F_IN * HF;
    if (j < HF * HF) {                         // W2t[nn*HF + k] = bf16(W2[k*HF + nn])
        int nn = j >> 8, k = j & (HF - 1);
        W2t[j] = f2bf(W2[(size_t)k * HF + nn]);
    }
}

// ---------- one packed 64-bit atomic per edge: deg-sum + count ----------
__global__ void count_pack_kernel(const int* __restrict__ col,
                                  const float* __restrict__ w,
                                  unsigned long long* __restrict__ packed, int e) {
    int i = blockIdx.x * blockDim.x + threadIdx.x;
    if (i < e) {
        unsigned long long add = (1ULL << 40)
            | (unsigned long long)__float2uint_rn(w[i] * 1048576.0f);
        atomicAdd(&packed[col[i]], add);
    }
}

// ---------- GEMM: C[M,Ntot](bf16) = A[M,K] @ Bt[Ntot,K]^T ----------
// BM=BN=128, BK=32; 4 waves, each a 64x64 subtile (4x4 MFMA 16x16x32).
// Operands SWAPPED in mfma -> each lane holds 4 consecutive C-cols of one row.
// Epilogue: pack->LDS (64-row halves) -> coalesced b128 row-major stores.
template<int A_IS_F32>
__device__ __forceinline__
void gemm_body(const void* __restrict__ Araw, const unsigned short* __restrict__ Bt,
               unsigned short* __restrict__ C, int Mvalid, int K, int Ntot,
               int mblk, int nblk, char* smem) {
    unsigned short* As = (unsigned short*)smem;          // 128*LDSTR
    unsigned short* Bs = As + 128 * LDSTR;               // 128*LDSTR
    const int tid  = threadIdx.x;
    const int lane = tid & 63;
    const int wv   = tid >> 6;
    const int wrow = wv >> 1, wcol = wv & 1;
    const int m0 = mblk * 128;
    const int n0 = nblk * 128;

    const int sr = tid >> 2;          // staging row 0..63
    const int sc = (tid & 3) * 8;     // staging k-offset 0,8,16,24

    f32x4 zero4 = {0.0f, 0.0f, 0.0f, 0.0f};
    f32x4 acc[4][4];
    #pragma unroll
    for (int i = 0; i < 4; ++i)
        #pragma unroll
        for (int j = 0; j < 4; ++j) acc[i][j] = zero4;

    const int q8 = (lane >> 4) * 8;
    const int ml = lane & 15;
    const int q4 = (lane >> 4) * 4;

    for (int k0 = 0; k0 < K; k0 += 32) {
        if (A_IS_F32) {
            const float* A = (const float*)Araw;
            #pragma unroll
            for (int h = 0; h < 2; ++h) {
                int rr = sr + h * 64;
                int gm = m0 + rr;
                float4 f0 = {0.f, 0.f, 0.f, 0.f}, f1 = {0.f, 0.f, 0.f, 0.f};
                if (gm < Mvalid) {
                    f0 = *(const float4*)(A + (size_t)gm * K + k0 + sc);
                    f1 = *(const float4*)(A + (size_t)gm * K + k0 + sc + 4);
                }
                bf16x8 v;
                v[0] = (short)f2bf(f0.x); v[1] = (short)f2bf(f0.y);
                v[2] = (short)f2bf(f0.z); v[3] = (short)f2bf(f0.w);
                v[4] = (short)f2bf(f1.x); v[5] = (short)f2bf(f1.y);
                v[6] = (short)f2bf(f1.z); v[7] = (short)f2bf(f1.w);
                *(bf16x8*)&As[rr * LDSTR + sc] = v;
            }
        } else {
            const unsigned short* A = (const unsigned short*)Araw;
            #pragma unroll
            for (int h = 0; h < 2; ++h) {
                int rr = sr + h * 64;
                int gm = m0 + rr;
                bf16x8 v = {0, 0, 0, 0, 0, 0, 0, 0};
                if (gm < Mvalid) v = *(const bf16x8*)(A + (size_t)gm * K + k0 + sc);
                *(bf16x8*)&As[rr * LDSTR + sc] = v;
            }
        }
        #pragma unroll
        for (int h = 0; h < 2; ++h) {
            int rr = sr + h * 64;
            bf16x8 v = *(const bf16x8*)(Bt + (size_t)(nblk * 128 + rr) * K + k0 + sc);
            *(bf16x8*)&Bs[rr * LDSTR + sc] = v;
        }
        __syncthreads();

        bf16x8 af[4], bfr[4];
        #pragma unroll
        for (int i = 0; i < 4; ++i)
            af[i] = *(const bf16x8*)&As[(wrow * 64 + i * 16 + ml) * LDSTR + q8];
        #pragma unroll
        for (int j = 0; j < 4; ++j)
            bfr[j] = *(const bf16x8*)&Bs[(wcol * 64 + j * 16 + ml) * LDSTR + q8];
        // SWAPPED operands: D row-dim = B's n (cols), D col-dim = A's m (rows)
        #pragma unroll
        for (int i = 0; i < 4; ++i)
            #pragma unroll
            for (int j = 0; j < 4; ++j)
                acc[i][j] = __builtin_amdgcn_mfma_f32_16x16x32_bf16(bfr[j], af[i], acc[i][j], 0, 0, 0);
        __syncthreads();
    }

    // ---- epilogue: per lane, tile (i,j) holds row i*16+ml, cols j*16+q4+rg ----
    unsigned short* Ep = (unsigned short*)smem;   // 64 x EPSTR shorts (17408 B)
    #pragma unroll
    for (int hh = 0; hh < 2; ++hh) {
        if (wrow == hh) {
            #pragma unroll
            for (int i = 0; i < 4; ++i) {
                #pragma unroll
                for (int j = 0; j < 4; ++j) {
                    short4 o;
                    o.x = (short)f2bf(acc[i][j][0]);
                    o.y = (short)f2bf(acc[i][j][1]);
                    o.z = (short)f2bf(acc[i][j][2]);
                    o.w = (short)f2bf(acc[i][j][3]);
                    *(short4*)&Ep[(i * 16 + ml) * EPSTR + wcol * 64 + j * 16 + q4] = o;
                }
            }
        }
        __syncthreads();
        #pragma unroll
        for (int rnd = 0; rnd < 4; ++rnd) {
            int rowh = (tid >> 4) + rnd * 16;    // 0..63
            int ch   = tid & 15;                 // 16-B chunk within 128-col row
            bf16x8 v = *(const bf16x8*)&Ep[rowh * EPSTR + ch * 8];
            int gr = m0 + hh * 64 + rowh;
            *(bf16x8*)(C + (size_t)gr * Ntot + n0 + ch * 8) = v;
        }
        __syncthreads();
    }
}

__global__ __launch_bounds__(256)
void gemm1_kernel(const float* __restrict__ x, const unsigned short* __restrict__ W1t,
                  unsigned short* __restrict__ C, int Mvalid) {
    __shared__ __align__(16) char smem[2 * 128 * LDSTR * 2];   // 18432 B (>= 64*EPSTR*2)
    gemm_body<1>(x, W1t, C, Mvalid, F_IN, HF, blockIdx.x, blockIdx.y, smem);
}

__global__ __launch_bounds__(256)
void gemm2_kernel(const unsigned short* __restrict__ A, const unsigned short* __restrict__ Bt,
                  unsigned short* __restrict__ C, int Mvalid) {
    __shared__ __align__(16) char smem[2 * 128 * LDSTR * 2];
    gemm_body<0>(A, Bt, C, Mvalid, HF, HF, blockIdx.x, blockIdx.y, smem);
}

// ---------- scan1: block-local exclusive scan of counts ----------
__global__ void scan1_kernel(const unsigned long long* __restrict__ packed,
                             int* __restrict__ local, int* __restrict__ blocksum, int n) {
    __shared__ int tmp[SCAN_B];
    int i = blockIdx.x * SCAN_B + threadIdx.x;
    int v = (i < n) ? (int)(packed[i] >> 40) : 0;
    tmp[threadIdx.x] = v;
    __syncthreads();
    for (int off = 1; off < SCAN_B; off <<= 1) {
        int t = 0;
        if ((int)threadIdx.x >= off) t = tmp[threadIdx.x - off];
        __syncthreads();
        if ((int)threadIdx.x >= off) tmp[threadIdx.x] += t;
        __syncthreads();
    }
    if (i < n) local[i] = tmp[threadIdx.x] - v;       // exclusive
    if (threadIdx.x == SCAN_B - 1) blocksum[blockIdx.x] = tmp[SCAN_B - 1];
}

// ---------- scan3: add block prefix (re-reduced in-block) + dinv ----------
__global__ void scan3_dinv_kernel(int* __restrict__ csr_ptr, int* __restrict__ cursor,
                                  const int* __restrict__ blocksum,
                                  const unsigned long long* __restrict__ packed,
                                  float* __restrict__ dinv, int n, int e, int nb) {
    __shared__ int red[SCAN_B];
    int t = threadIdx.x;
    red[t] = (t < nb && t < (int)blockIdx.x) ? blocksum[t] : 0;
    __syncthreads();
    for (int off = SCAN_B / 2; off > 0; off >>= 1) {
        if (t < off) red[t] += red[t + off];
        __syncthreads();
    }
    int prefix = red[0];
    int i = blockIdx.x * SCAN_B + t;
    if (i < n) {
        int val = csr_ptr[i] + prefix;
        csr_ptr[i] = val;
        cursor[i] = val;
        float deg = (float)(packed[i] & 0xFFFFFFFFFFULL) * (1.0f / 1048576.0f);
        dinv[i] = rsqrtf(deg);   // deg >= 1 always (self-loop)
    }
    if (i == 0) csr_ptr[n] = e;
}

// ---------- CSR fill: bucket edges by col, fold norm, 8B paired store ----------
__global__ void fill_kernel(const int* __restrict__ row, const int* __restrict__ col,
                            const float* __restrict__ w, const float* __restrict__ dinv,
                            int* __restrict__ cursor, int2* __restrict__ csr_edge, int e) {
    int i = blockIdx.x * blockDim.x + threadIdx.x;
    if (i < e) {
        int r = row[i], c = col[i];
        int pos = atomicAdd(&cursor[c], 1);
        float nrm = dinv[r] * w[i] * dinv[c];
        csr_edge[pos] = make_int2(r, __float_as_int(nrm));
    }
}

// ---------- fused CSR gather + self-loop + bias + BN + ReLU ----------
// one wave per node; unconditional batches of 8, clamped masked tail.
// FINAL=1: additionally computes h3[node,2] = act . W3 (wave reduce), skips bf16 store.
template<int FINAL>
__global__ void agg_kernel(const unsigned short* __restrict__ h,
                           const int* __restrict__ ptr,
                           const int2* __restrict__ edge,
                           const float* __restrict__ dinv,
                           const float* __restrict__ b, const float* __restrict__ g,
                           const float* __restrict__ be, const float* __restrict__ m,
                           const float* __restrict__ v,
                           unsigned short* __restrict__ out,
                           const float* __restrict__ W3, float* __restrict__ h3, int n) {
    int wid  = (blockIdx.x * blockDim.x + threadIdx.x) >> 6;
    int lane = threadIdx.x & 63;
    if (wid >= n) return;
    int p0 = ptr[wid], p1 = ptr[wid + 1];
    const int fo = lane * 4;
    float a0 = 0.f, a1 = 0.f, a2 = 0.f, a3 = 0.f;

    const int pend = p0 + ((p1 - p0) & ~7);
    for (int p = p0; p < pend; p += 8) {
        int2 ed[8];
        #pragma unroll
        for (int k = 0; k < 8; ++k) ed[k] = edge[p + k];
        ushort4 hv[8];
        #pragma unroll
        for (int k = 0; k < 8; ++k)
            hv[k] = *(const ushort4*)(h + (size_t)ed[k].x * HF + fo);
        #pragma unroll
        for (int k = 0; k < 8; ++k) {
            float nw = __int_as_float(ed[k].y);
            a0 += nw * bf2f(hv[k].x);
            a1 += nw * bf2f(hv[k].y);
            a2 += nw * bf2f(hv[k].z);
            a3 += nw * bf2f(hv[k].w);
        }
    }
    if (pend < p1) {   // masked tail batch of 8
        int2 ed[8];
        float wv[8];
        #pragma unroll
        for (int k = 0; k < 8; ++k) {
            int idx = pend + k < p1 ? pend + k : p1 - 1;
            ed[k] = edge[idx];
            wv[k] = (pend + k < p1) ? __int_as_float(ed[k].y) : 0.0f;
        }
        ushort4 hv[8];
        #pragma unroll
        for (int k = 0; k < 8; ++k)
            hv[k] = *(const ushort4*)(h + (size_t)ed[k].x * HF + fo);
        #pragma unroll
        for (int k = 0; k < 8; ++k) {
            a0 += wv[k] * bf2f(hv[k].x);
            a1 += wv[k] * bf2f(hv[k].y);
            a2 += wv[k] * bf2f(hv[k].z);
            a3 += wv[k] * bf2f(hv[k].w);
        }
    }
    // self loop: weight 1, norm = dinv^2
    float s = dinv[wid];
    float sl = s * s;
    ushort4 hv = *(const ushort4*)(h + (size_t)wid * HF + fo);
    a0 += sl * bf2f(hv.x);
    a1 += sl * bf2f(hv.y);
    a2 += sl * bf2f(hv.z);
    a3 += sl * bf2f(hv.w);

    float4 bb  = *(const float4*)(b + fo);
    float4 gg  = *(const float4*)(g + fo);
    float4 bee = *(const float4*)(be + fo);
    float4 mm  = *(const float4*)(m + fo);
    float4 vv  = *(const float4*)(v + fo);
    float f0 = fmaxf((a0 + bb.x - mm.x) * rsqrtf(vv.x + BN_EPS) * gg.x + bee.x, 0.f);
    float f1 = fmaxf((a1 + bb.y - mm.y) * rsqrtf(vv.y + BN_EPS) * gg.y + bee.y, 0.f);
    float f2 = fmaxf((a2 + bb.z - mm.z) * rsqrtf(vv.z + BN_EPS) * gg.z + bee.z, 0.f);
    float f3 = fmaxf((a3 + bb.w - mm.w) * rsqrtf(vv.w + BN_EPS) * gg.w + bee.w, 0.f);

    if (!FINAL) {
        ushort4 o;
        o.x = f2bf(f0); o.y = f2bf(f1); o.z = f2bf(f2); o.w = f2bf(f3);
        *(ushort4*)(out + (size_t)wid * HF + fo) = o;
    } else {
        // fused layer-3 GEMV: h3[wid, o] = sum_f act[f] * W3[f][o]
        float4 w0 = *(const float4*)(W3 + fo * 2);
        float4 w1 = *(const float4*)(W3 + fo * 2 + 4);
        float s0 = f0 * w0.x + f1 * w0.z + f2 * w1.x + f3 * w1.z;
        float s1 = f0 * w0.y + f1 * w0.w + f2 * w1.y + f3 * w1.w;
        #pragma unroll
        for (int o = 32; o > 0; o >>= 1) {
            s0 += __shfl_down(s0, o, 64);
            s1 += __shfl_down(s1, o, 64);
        }
        if (lane == 0) {
            h3[wid * 2 + 0] = s0;
            h3[wid * 2 + 1] = s1;
        }
    }
}

// ---------- final: CSR gather (2 features) + self-loop + bias ----------
__global__ void out_kernel(const float* __restrict__ h3,
                           const int* __restrict__ ptr, const int2* __restrict__ edge,
                           const float* __restrict__ dinv,
                           const float* __restrict__ b3, float* __restrict__ out, int n) {
    int i = blockIdx.x * blockDim.x + threadIdx.x;
    if (i >= n) return;
    int p0 = ptr[i], p1 = ptr[i + 1];
    float a0 = 0.f, a1 = 0.f;
    for (int p = p0; p < p1; p += 4) {
        #pragma unroll
        for (int k = 0; k < 4; ++k) {
            int idx = p + k < p1 ? p + k : p1 - 1;
            int2 e = edge[idx];
            float nw = (p + k < p1) ? __int_as_float(e.y) : 0.0f;
            float2 u = *(const float2*)(h3 + 2 * e.x);
            a0 += nw * u.x;
            a1 += nw * u.y;
        }
    }
    float s = dinv[i];
    float sl = s * s;
    out[2 * i + 0] = a0 + sl * h3[2 * i + 0] + b3[0];
    out[2 * i + 1] = a1 + sl * h3[2 * i + 1] + b3[1];
}

static inline char* align16(char* p) {
    return (char*)(((uintptr_t)p + 15) & ~(uintptr_t)15);
}

extern "C" void kernel_launch(void* const* d_in, const int* in_sizes, int n_in,
                              void* d_out, int out_size, void* d_ws, size_t ws_size,
                              hipStream_t stream) {
    const float* x   = (const float*)d_in[0];
    const int*   ei  = (const int*)d_in[1];    // int64 in reference -> int32 in harness
    const float* ew  = (const float*)d_in[2];
    const float* W1  = (const float*)d_in[3];
    const float* b1  = (const float*)d_in[4];
    const float* g1  = (const float*)d_in[5];
    const float* be1 = (const float*)d_in[6];
    const float* m1  = (const float*)d_in[7];
    const float* v1  = (const float*)d_in[8];
    const float* W2  = (const float*)d_in[9];
    const float* b2  = (const float*)d_in[10];
    const float* g2  = (const float*)d_in[11];
    const float* be2 = (const float*)d_in[12];
    const float* m2  = (const float*)d_in[13];
    const float* v2  = (const float*)d_in[14];
    const float* W3  = (const float*)d_in[15];
    const float* b3  = (const float*)d_in[16];

    const int N  = in_sizes[0] / F_IN;         // 50000
    const int E  = in_sizes[2];                // 800000
    const int MP = (N + 127) & ~127;           // 50048
    const int* row = ei;
    const int* col = ei + E;

    char* wsb = (char*)d_ws;
    unsigned long long* packed = (unsigned long long*)wsb; wsb = align16(wsb + (size_t)N * 8);
    float* dinv     = (float*)wsb;          wsb = align16(wsb + (size_t)N * 4);
    int*   csr_ptr  = (int*)wsb;            wsb = align16(wsb + (size_t)(N + 1) * 4);
    int*   cursor   = (int*)wsb;            wsb = align16(wsb + (size_t)N * 4);
    int*   blocksum = (int*)wsb;            wsb = align16(wsb + (size_t)SCAN_B * 4);
    int2*  csr_edge = (int2*)wsb;           wsb = align16(wsb + (size_t)E * 8);
    unsigned short* W1t = (unsigned short*)wsb;  wsb = align16(wsb + (size_t)F_IN * HF * 2);
    unsigned short* W2t = (unsigned short*)wsb;  wsb = align16(wsb + (size_t)HF * HF * 2);
    unsigned short* bufh = (unsigned short*)wsb; wsb = align16(wsb + (size_t)MP * HF * 2);
    unsigned short* bufa = (unsigned short*)wsb; wsb = align16(wsb + (size_t)MP * HF * 2);
    float* h3 = (float*)wsb;                wsb = align16(wsb + (size_t)N * OUT_F * 4);
    float* outf = (float*)d_out;

    const int TB = 256;
    const int nscan = (N + SCAN_B - 1) / SCAN_B;        // 196
    const int preptot = N + F_IN * HF + HF * HF;

    // --- prep: packed init + weight transposes ---
    prep_kernel<<<(preptot + TB - 1) / TB, TB, 0, stream>>>(packed, W1, W1t, W2, W2t, N);

    // --- graph preprocessing (graph identical across all 3 layers) ---
    count_pack_kernel<<<(E + TB - 1) / TB, TB, 0, stream>>>(col, ew, packed, E);
    scan1_kernel<<<nscan, SCAN_B, 0, stream>>>(packed, csr_ptr, blocksum, N);
    scan3_dinv_kernel<<<nscan, SCAN_B, 0, stream>>>(csr_ptr, cursor, blocksum, packed, dinv, N, E, nscan);
    fill_kernel<<<(E + TB - 1) / TB, TB, 0, stream>>>(row, col, ew, dinv, cursor, csr_edge, E);

    dim3 ggrid(MP / 128, HF / 128);   // (391, 2)

    // --- layer 1 ---
    gemm1_kernel<<<ggrid, TB, 0, stream>>>(x, W1t, bufh, N);
    agg_kernel<0><<<((size_t)N * 64 + TB - 1) / TB, TB, 0, stream>>>(
        bufh, csr_ptr, csr_edge, dinv, b1, g1, be1, m1, v1, bufa, nullptr, nullptr, N);

    // --- layer 2 ---
    gemm2_kernel<<<ggrid, TB, 0, stream>>>(bufa, W2t, bufh, N);
    agg_kernel<1><<<((size_t)N * 64 + TB - 1) / TB, TB, 0, stream>>>(
        bufh, csr_ptr, csr_edge, dinv, b2, g2, be2, m2, v2, nullptr, W3, h3, N);

    // --- final 2-feature aggregation ---
    out_kernel<<<(N + TB - 1) / TB, TB, 0, stream>>>(h3, csr_ptr, csr_edge, dinv, b3, outf, N);
}

// Round 10
// 492.507 us; speedup vs baseline: 1.2954x; 1.0860x over previous
//
#include <hip/hip_runtime.h>
#include <stdint.h>

#define F_IN 512
#define HF 256
#define OUT_F 2
#define BN_EPS 1e-5f
#define SCAN_B 256
#define LDSTR 36    // LDS row stride (shorts): 0 bank conflicts (measured R7)

typedef __attribute__((ext_vector_type(8))) short bf16x8;
typedef __attribute__((ext_vector_type(4))) float f32x4;

__device__ inline float bf2f(unsigned short u) {
    union { float f; uint32_t i; } v; v.i = ((uint32_t)u) << 16; return v.f;
}
__device__ inline unsigned short f2bf(float f) {
    union { float f; uint32_t i; } v; v.f = f;
    uint32_t r = v.i + 0x7FFFu + ((v.i >> 16) & 1u);   // RNE (finite values only)
    return (unsigned short)(r >> 16);
}

// ---------- prep: packed init + weight transposes + pad-row zeroing ----------
__global__ void prep_kernel(unsigned long long* __restrict__ packed,
                            const float* __restrict__ W1, unsigned short* __restrict__ W1t,
                            const float* __restrict__ W2, unsigned short* __restrict__ W2t,
                            unsigned short* __restrict__ xbf_pad,   // xbf + N*F_IN
                            unsigned short* __restrict__ bufa_pad,  // bufa + N*HF
                            int n, int padx, int pada) {
    int idx = blockIdx.x * blockDim.x + threadIdx.x;
    if (idx < n) { packed[idx] = 1ULL << 20; return; }   // self-loop w=1.0, 24.20 fixpoint
    int j = idx - n;
    if (j < F_IN * HF) {                       // W1t[nn*F_IN + k] = bf16(W1[k*HF + nn])
        int nn = j >> 9, k = j & (F_IN - 1);
        W1t[j] = f2bf(W1[(size_t)k * HF + nn]);
        return;
    }
    j -= F_IN * HF;
    if (j < HF * HF) {                         // W2t[nn*HF + k] = bf16(W2[k*HF + nn])
        int nn = j >> 8, k = j & (HF - 1);
        W2t[j] = f2bf(W2[(size_t)k * HF + nn]);
        return;
    }
    j -= HF * HF;
    if (j < padx) { xbf_pad[j] = 0; return; }
    j -= padx;
    if (j < pada) bufa_pad[j] = 0;
}

// ---------- count (packed 64-bit atomic per edge) + x -> bf16 conversion ----------
__global__ void count_conv_kernel(const int* __restrict__ col,
                                  const float* __restrict__ w,
                                  unsigned long long* __restrict__ packed,
                                  const float* __restrict__ x,
                                  unsigned short* __restrict__ xbf,
                                  int e, int nchunk) {
    int tid = blockIdx.x * blockDim.x + threadIdx.x;
    int base = blockIdx.x * 1024 + (int)threadIdx.x;
    #pragma unroll
    for (int k = 0; k < 4; ++k) {
        int i = base + k * 256;
        if (i < e) {
            unsigned long long add = (1ULL << 40)
                | (unsigned long long)__float2uint_rn(w[i] * 1048576.0f);
            atomicAdd(&packed[col[i]], add);
        }
    }
    // grid-stride fp32 -> bf16 (8 elems per chunk)
    const int stride = gridDim.x * blockDim.x;
    const float4* x4 = (const float4*)x;
    for (int c = tid; c < nchunk; c += stride) {
        float4 f0 = x4[2 * c];
        float4 f1 = x4[2 * c + 1];
        bf16x8 v;
        v[0] = (short)f2bf(f0.x); v[1] = (short)f2bf(f0.y);
        v[2] = (short)f2bf(f0.z); v[3] = (short)f2bf(f0.w);
        v[4] = (short)f2bf(f1.x); v[5] = (short)f2bf(f1.y);
        v[6] = (short)f2bf(f1.z); v[7] = (short)f2bf(f1.w);
        *(bf16x8*)(xbf + (size_t)c * 8) = v;
    }
}

// ---------- pipelined bf16 GEMM: C[MP,256] = A[MP,K] @ Bt[256,K]^T ----------
// BM=BN=128, BK=32; 4 waves, 64x64 subtile each (4x4 MFMA 16x16x32).
// Register prefetch + LDS double-buffer: ONE barrier per K-step; global loads
// for step s+1 issue before MFMA of step s (latency overlapped).
__global__ __launch_bounds__(256)
void gemm_kernel(const unsigned short* __restrict__ A,
                 const unsigned short* __restrict__ Bt,
                 unsigned short* __restrict__ C, int K) {
    __shared__ unsigned short As[2][128 * LDSTR];
    __shared__ unsigned short Bs[2][128 * LDSTR];
    const int tid  = threadIdx.x;
    const int lane = tid & 63;
    const int wv   = tid >> 6;
    const int wrow = wv >> 1, wcol = wv & 1;
    const int m0 = blockIdx.x * 128;
    const int n0 = blockIdx.y * 128;

    const int sr = tid >> 2;          // staging row 0..63
    const int sc = (tid & 3) * 8;     // staging k-offset 0,8,16,24

    const unsigned short* pa0 = A + (size_t)(m0 + sr) * K + sc;
    const unsigned short* pa1 = A + (size_t)(m0 + sr + 64) * K + sc;
    const unsigned short* pb0 = Bt + (size_t)(n0 + sr) * K + sc;
    const unsigned short* pb1 = Bt + (size_t)(n0 + sr + 64) * K + sc;

    f32x4 zero4 = {0.0f, 0.0f, 0.0f, 0.0f};
    f32x4 acc[4][4];
    #pragma unroll
    for (int i = 0; i < 4; ++i)
        #pragma unroll
        for (int j = 0; j < 4; ++j) acc[i][j] = zero4;

    const int q8 = (lane >> 4) * 8;
    const int ml = lane & 15;

    bf16x8 va0 = *(const bf16x8*)pa0;
    bf16x8 va1 = *(const bf16x8*)pa1;
    bf16x8 vb0 = *(const bf16x8*)pb0;
    bf16x8 vb1 = *(const bf16x8*)pb1;

    const int nsteps = K >> 5;
    for (int s = 0; s < nsteps; ++s) {
        const int buf = s & 1;
        *(bf16x8*)&As[buf][sr * LDSTR + sc]        = va0;
        *(bf16x8*)&As[buf][(sr + 64) * LDSTR + sc] = va1;
        *(bf16x8*)&Bs[buf][sr * LDSTR + sc]        = vb0;
        *(bf16x8*)&Bs[buf][(sr + 64) * LDSTR + sc] = vb1;
        __syncthreads();
        if (s + 1 < nsteps) {             // prefetch next tile; waits land at next LDS write
            int off = (s + 1) * 32;
            va0 = *(const bf16x8*)(pa0 + off);
            va1 = *(const bf16x8*)(pa1 + off);
            vb0 = *(const bf16x8*)(pb0 + off);
            vb1 = *(const bf16x8*)(pb1 + off);
        }
        bf16x8 af[4], bfr[4];
        #pragma unroll
        for (int i = 0; i < 4; ++i)
            af[i] = *(const bf16x8*)&As[buf][(wrow * 64 + i * 16 + ml) * LDSTR + q8];
        #pragma unroll
        for (int j = 0; j < 4; ++j)
            bfr[j] = *(const bf16x8*)&Bs[buf][(wcol * 64 + j * 16 + ml) * LDSTR + q8];
        #pragma unroll
        for (int i = 0; i < 4; ++i)
            #pragma unroll
            for (int j = 0; j < 4; ++j)
                acc[i][j] = __builtin_amdgcn_mfma_f32_16x16x32_bf16(af[i], bfr[j], acc[i][j], 0, 0, 0);
        // no trailing barrier: next write targets the other buffer; the single
        // barrier above orders write(k) .. read(k) and read(k) .. write(k+2).
    }

    // C store (bf16): col=lane&15, row=(lane>>4)*4+reg  (R5-verified path)
    const int q4 = (lane >> 4) * 4;
    #pragma unroll
    for (int i = 0; i < 4; ++i) {
        #pragma unroll
        for (int j = 0; j < 4; ++j) {
            #pragma unroll
            for (int rg = 0; rg < 4; ++rg) {
                int r = m0 + wrow * 64 + i * 16 + q4 + rg;
                int c = n0 + wcol * 64 + j * 16 + ml;
                C[(size_t)r * HF + c] = f2bf(acc[i][j][rg]);
            }
        }
    }
}

// ---------- scan1: block-local exclusive scan of counts ----------
__global__ void scan1_kernel(const unsigned long long* __restrict__ packed,
                             int* __restrict__ local, int* __restrict__ blocksum, int n) {
    __shared__ int tmp[SCAN_B];
    int i = blockIdx.x * SCAN_B + threadIdx.x;
    int v = (i < n) ? (int)(packed[i] >> 40) : 0;
    tmp[threadIdx.x] = v;
    __syncthreads();
    for (int off = 1; off < SCAN_B; off <<= 1) {
        int t = 0;
        if ((int)threadIdx.x >= off) t = tmp[threadIdx.x - off];
        __syncthreads();
        if ((int)threadIdx.x >= off) tmp[threadIdx.x] += t;
        __syncthreads();
    }
    if (i < n) local[i] = tmp[threadIdx.x] - v;       // exclusive
    if (threadIdx.x == SCAN_B - 1) blocksum[blockIdx.x] = tmp[SCAN_B - 1];
}

// ---------- scan3: add block prefix (re-reduced in-block) + dinv ----------
__global__ void scan3_dinv_kernel(int* __restrict__ csr_ptr, int* __restrict__ cursor,
                                  const int* __restrict__ blocksum,
                                  const unsigned long long* __restrict__ packed,
                                  float* __restrict__ dinv, int n, int e, int nb) {
    __shared__ int red[SCAN_B];
    int t = threadIdx.x;
    red[t] = (t < nb && t < (int)blockIdx.x) ? blocksum[t] : 0;
    __syncthreads();
    for (int off = SCAN_B / 2; off > 0; off >>= 1) {
        if (t < off) red[t] += red[t + off];
        __syncthreads();
    }
    int prefix = red[0];
    int i = blockIdx.x * SCAN_B + t;
    if (i < n) {
        int val = csr_ptr[i] + prefix;
        csr_ptr[i] = val;
        cursor[i] = val;
        float deg = (float)(packed[i] & 0xFFFFFFFFFFULL) * (1.0f / 1048576.0f);
        dinv[i] = rsqrtf(deg);   // deg >= 1 always (self-loop)
    }
    if (i == 0) csr_ptr[n] = e;
}

// ---------- CSR fill: bucket edges by col, fold norm, 8B paired store ----------
__global__ void fill_kernel(const int* __restrict__ row, const int* __restrict__ col,
                            const float* __restrict__ w, const float* __restrict__ dinv,
                            int* __restrict__ cursor, int2* __restrict__ csr_edge, int e) {
    int i = blockIdx.x * blockDim.x + threadIdx.x;
    if (i < e) {
        int r = row[i], c = col[i];
        int pos = atomicAdd(&cursor[c], 1);
        float nrm = dinv[r] * w[i] * dinv[c];
        csr_edge[pos] = make_int2(r, __float_as_int(nrm));
    }
}

// ---------- fused CSR gather + self-loop + bias + BN + ReLU ----------
// one wave per node; unconditional batches of 8, clamped masked tail.
// FINAL=1: additionally computes h3[node,2] = act . W3 (wave reduce), skips bf16 store.
template<int FINAL>
__global__ void agg_kernel(const unsigned short* __restrict__ h,
                           const int* __restrict__ ptr,
                           const int2* __restrict__ edge,
                           const float* __restrict__ dinv,
                           const float* __restrict__ b, const float* __restrict__ g,
                           const float* __restrict__ be, const float* __restrict__ m,
                           const float* __restrict__ v,
                           unsigned short* __restrict__ out,
                           const float* __restrict__ W3, float* __restrict__ h3, int n) {
    int wid  = (blockIdx.x * blockDim.x + threadIdx.x) >> 6;
    int lane = threadIdx.x & 63;
    if (wid >= n) return;
    int p0 = ptr[wid], p1 = ptr[wid + 1];
    const int fo = lane * 4;
    float a0 = 0.f, a1 = 0.f, a2 = 0.f, a3 = 0.f;

    const int pend = p0 + ((p1 - p0) & ~7);
    for (int p = p0; p < pend; p += 8) {
        int2 ed[8];
        #pragma unroll
        for (int k = 0; k < 8; ++k) ed[k] = edge[p + k];
        ushort4 hv[8];
        #pragma unroll
        for (int k = 0; k < 8; ++k)
            hv[k] = *(const ushort4*)(h + (size_t)ed[k].x * HF + fo);
        #pragma unroll
        for (int k = 0; k < 8; ++k) {
            float nw = __int_as_float(ed[k].y);
            a0 += nw * bf2f(hv[k].x);
            a1 += nw * bf2f(hv[k].y);
            a2 += nw * bf2f(hv[k].z);
            a3 += nw * bf2f(hv[k].w);
        }
    }
    if (pend < p1) {   // masked tail batch of 8
        int2 ed[8];
        float wv[8];
        #pragma unroll
        for (int k = 0; k < 8; ++k) {
            int idx = pend + k < p1 ? pend + k : p1 - 1;
            ed[k] = edge[idx];
            wv[k] = (pend + k < p1) ? __int_as_float(ed[k].y) : 0.0f;
        }
        ushort4 hv[8];
        #pragma unroll
        for (int k = 0; k < 8; ++k)
            hv[k] = *(const ushort4*)(h + (size_t)ed[k].x * HF + fo);
        #pragma unroll
        for (int k = 0; k < 8; ++k) {
            a0 += wv[k] * bf2f(hv[k].x);
            a1 += wv[k] * bf2f(hv[k].y);
            a2 += wv[k] * bf2f(hv[k].z);
            a3 += wv[k] * bf2f(hv[k].w);
        }
    }
    // self loop: weight 1, norm = dinv^2
    float s = dinv[wid];
    float sl = s * s;
    ushort4 hv = *(const ushort4*)(h + (size_t)wid * HF + fo);
    a0 += sl * bf2f(hv.x);
    a1 += sl * bf2f(hv.y);
    a2 += sl * bf2f(hv.z);
    a3 += sl * bf2f(hv.w);

    float4 bb  = *(const float4*)(b + fo);
    float4 gg  = *(const float4*)(g + fo);
    float4 bee = *(const float4*)(be + fo);
    float4 mm  = *(const float4*)(m + fo);
    float4 vv  = *(const float4*)(v + fo);
    float f0 = fmaxf((a0 + bb.x - mm.x) * rsqrtf(vv.x + BN_EPS) * gg.x + bee.x, 0.f);
    float f1 = fmaxf((a1 + bb.y - mm.y) * rsqrtf(vv.y + BN_EPS) * gg.y + bee.y, 0.f);
    float f2 = fmaxf((a2 + bb.z - mm.z) * rsqrtf(vv.z + BN_EPS) * gg.z + bee.z, 0.f);
    float f3 = fmaxf((a3 + bb.w - mm.w) * rsqrtf(vv.w + BN_EPS) * gg.w + bee.w, 0.f);

    if (!FINAL) {
        ushort4 o;
        o.x = f2bf(f0); o.y = f2bf(f1); o.z = f2bf(f2); o.w = f2bf(f3);
        *(ushort4*)(out + (size_t)wid * HF + fo) = o;
    } else {
        // fused layer-3 GEMV: h3[wid, o] = sum_f act[f] * W3[f][o]
        float4 w0 = *(const float4*)(W3 + fo * 2);
        float4 w1 = *(const float4*)(W3 + fo * 2 + 4);
        float s0 = f0 * w0.x + f1 * w0.z + f2 * w1.x + f3 * w1.z;
        float s1 = f0 * w0.y + f1 * w0.w + f2 * w1.y + f3 * w1.w;
        #pragma unroll
        for (int o = 32; o > 0; o >>= 1) {
            s0 += __shfl_down(s0, o, 64);
            s1 += __shfl_down(s1, o, 64);
        }
        if (lane == 0) {
            h3[wid * 2 + 0] = s0;
            h3[wid * 2 + 1] = s1;
        }
    }
}

// ---------- final: CSR gather (2 features) + self-loop + bias ----------
__global__ void out_kernel(const float* __restrict__ h3,
                           const int* __restrict__ ptr, const int2* __restrict__ edge,
                           const float* __restrict__ dinv,
                           const float* __restrict__ b3, float* __restrict__ out, int n) {
    int i = blockIdx.x * blockDim.x + threadIdx.x;
    if (i >= n) return;
    int p0 = ptr[i], p1 = ptr[i + 1];
    float a0 = 0.f, a1 = 0.f;
    for (int p = p0; p < p1; p += 4) {
        #pragma unroll
        for (int k = 0; k < 4; ++k) {
            int idx = p + k < p1 ? p + k : p1 - 1;
            int2 e = edge[idx];
            float nw = (p + k < p1) ? __int_as_float(e.y) : 0.0f;
            float2 u = *(const float2*)(h3 + 2 * e.x);
            a0 += nw * u.x;
            a1 += nw * u.y;
        }
    }
    float s = dinv[i];
    float sl = s * s;
    out[2 * i + 0] = a0 + sl * h3[2 * i + 0] + b3[0];
    out[2 * i + 1] = a1 + sl * h3[2 * i + 1] + b3[1];
}

static inline char* align16(char* p) {
    return (char*)(((uintptr_t)p + 15) & ~(uintptr_t)15);
}

extern "C" void kernel_launch(void* const* d_in, const int* in_sizes, int n_in,
                              void* d_out, int out_size, void* d_ws, size_t ws_size,
                              hipStream_t stream) {
    const float* x   = (const float*)d_in[0];
    const int*   ei  = (const int*)d_in[1];    // int64 in reference -> int32 in harness
    const float* ew  = (const float*)d_in[2];
    const float* W1  = (const float*)d_in[3];
    const float* b1  = (const float*)d_in[4];
    const float* g1  = (const float*)d_in[5];
    const float* be1 = (const float*)d_in[6];
    const float* m1  = (const float*)d_in[7];
    const float* v1  = (const float*)d_in[8];
    const float* W2  = (const float*)d_in[9];
    const float* b2  = (const float*)d_in[10];
    const float* g2  = (const float*)d_in[11];
    const float* be2 = (const float*)d_in[12];
    const float* m2  = (const float*)d_in[13];
    const float* v2  = (const float*)d_in[14];
    const float* W3  = (const float*)d_in[15];
    const float* b3  = (const float*)d_in[16];

    const int N  = in_sizes[0] / F_IN;         // 50000
    const int E  = in_sizes[2];                // 800000
    const int MP = (N + 127) & ~127;           // 50048
    const int* row = ei;
    const int* col = ei + E;

    char* wsb = (char*)d_ws;
    unsigned long long* packed = (unsigned long long*)wsb; wsb = align16(wsb + (size_t)N * 8);
    float* dinv     = (float*)wsb;          wsb = align16(wsb + (size_t)N * 4);
    int*   csr_ptr  = (int*)wsb;            wsb = align16(wsb + (size_t)(N + 1) * 4);
    int*   cursor   = (int*)wsb;            wsb = align16(wsb + (size_t)N * 4);
    int*   blocksum = (int*)wsb;            wsb = align16(wsb + (size_t)SCAN_B * 4);
    int2*  csr_edge = (int2*)wsb;           wsb = align16(wsb + (size_t)E * 8);
    unsigned short* W1t = (unsigned short*)wsb;  wsb = align16(wsb + (size_t)F_IN * HF * 2);
    unsigned short* W2t = (unsigned short*)wsb;  wsb = align16(wsb + (size_t)HF * HF * 2);
    unsigned short* xbf  = (unsigned short*)wsb; wsb = align16(wsb + (size_t)MP * F_IN * 2);
    unsigned short* bufh = (unsigned short*)wsb; wsb = align16(wsb + (size_t)MP * HF * 2);
    unsigned short* bufa = (unsigned short*)wsb; wsb = align16(wsb + (size_t)MP * HF * 2);
    float* h3 = (float*)wsb;                wsb = align16(wsb + (size_t)N * OUT_F * 4);
    float* outf = (float*)d_out;

    const int TB = 256;
    const int nscan = (N + SCAN_B - 1) / SCAN_B;        // 196
    const int padx = (MP - N) * F_IN;
    const int pada = (MP - N) * HF;
    const int preptot = N + F_IN * HF + HF * HF + padx + pada;
    const int ncount = (E + 1023) / 1024;               // 782
    const int nchunk = (N * F_IN) / 8;                  // 1.6M bf16x8 chunks

    // --- prep: packed init + weight transposes + pad zeroing ---
    prep_kernel<<<(preptot + TB - 1) / TB, TB, 0, stream>>>(
        packed, W1, W1t, W2, W2t, xbf + (size_t)N * F_IN, bufa + (size_t)N * HF, N, padx, pada);

    // --- count atomics + x->bf16 conversion (conversion hides under atomic latency) ---
    count_conv_kernel<<<ncount, TB, 0, stream>>>(col, ew, packed, x, xbf, E, nchunk);

    // --- CSR build ---
    scan1_kernel<<<nscan, SCAN_B, 0, stream>>>(packed, csr_ptr, blocksum, N);
    scan3_dinv_kernel<<<nscan, SCAN_B, 0, stream>>>(csr_ptr, cursor, blocksum, packed, dinv, N, E, nscan);
    fill_kernel<<<(E + TB - 1) / TB, TB, 0, stream>>>(row, col, ew, dinv, cursor, csr_edge, E);

    dim3 ggrid(MP / 128, HF / 128);   // (391, 2)

    // --- layer 1 ---
    gemm_kernel<<<ggrid, TB, 0, stream>>>(xbf, W1t, bufh, F_IN);
    agg_kernel<0><<<((size_t)N * 64 + TB - 1) / TB, TB, 0, stream>>>(
        bufh, csr_ptr, csr_edge, dinv, b1, g1, be1, m1, v1, bufa, nullptr, nullptr, N);

    // --- layer 2 ---
    gemm_kernel<<<ggrid, TB, 0, stream>>>(bufa, W2t, bufh, HF);
    agg_kernel<1><<<((size_t)N * 64 + TB - 1) / TB, TB, 0, stream>>>(
        bufh, csr_ptr, csr_edge, dinv, b2, g2, be2, m2, v2, nullptr, W3, h3, N);

    // --- final 2-feature aggregation ---
    out_kernel<<<(N + TB - 1) / TB, TB, 0, stream>>>(h3, csr_ptr, csr_edge, dinv, b3, outf, N);
}

// Round 11
// 468.265 us; speedup vs baseline: 1.3625x; 1.0518x over previous
//
#include <hip/hip_runtime.h>
#include <stdint.h>

#define F_IN 512
#define HF 256
#define OUT_F 2
#define BN_EPS 1e-5f
#define SCAN_B 256
#define LDSTR 36    // LDS row stride (shorts): 0 bank conflicts (measured R7)

typedef __attribute__((ext_vector_type(8))) short bf16x8;
typedef __attribute__((ext_vector_type(4))) float f32x4;

__device__ inline float bf2f(unsigned short u) {
    union { float f; uint32_t i; } v; v.i = ((uint32_t)u) << 16; return v.f;
}
__device__ inline unsigned short f2bf(float f) {
    union { float f; uint32_t i; } v; v.f = f;
    uint32_t r = v.i + 0x7FFFu + ((v.i >> 16) & 1u);   // RNE (finite values only)
    return (unsigned short)(r >> 16);
}

// ---------- prep: packed init + weight transposes + pad-row zeroing ----------
__global__ void prep_kernel(unsigned long long* __restrict__ packed,
                            const float* __restrict__ W1, unsigned short* __restrict__ W1t,
                            const float* __restrict__ W2, unsigned short* __restrict__ W2t,
                            unsigned short* __restrict__ xbf_pad,   // xbf + N*F_IN
                            unsigned short* __restrict__ bufa_pad,  // bufa + N*HF
                            int n, int padx, int pada) {
    int idx = blockIdx.x * blockDim.x + threadIdx.x;
    if (idx < n) { packed[idx] = 1ULL << 20; return; }   // self-loop w=1.0, 24.20 fixpoint
    int j = idx - n;
    if (j < F_IN * HF) {                       // W1t[nn*F_IN + k] = bf16(W1[k*HF + nn])
        int nn = j >> 9, k = j & (F_IN - 1);
        W1t[j] = f2bf(W1[(size_t)k * HF + nn]);
        return;
    }
    j -= F_IN * HF;
    if (j < HF * HF) {                         // W2t[nn*HF + k] = bf16(W2[k*HF + nn])
        int nn = j >> 8, k = j & (HF - 1);
        W2t[j] = f2bf(W2[(size_t)k * HF + nn]);
        return;
    }
    j -= HF * HF;
    if (j < padx) { xbf_pad[j] = 0; return; }
    j -= padx;
    if (j < pada) bufa_pad[j] = 0;
}

// ---------- count (packed 64-bit atomic, one edge/thread) + x -> bf16 ----------
__global__ void count_conv_kernel(const int* __restrict__ col,
                                  const float* __restrict__ w,
                                  unsigned long long* __restrict__ packed,
                                  const float* __restrict__ x,
                                  unsigned short* __restrict__ xbf,
                                  int e, int nchunk) {
    int tid = blockIdx.x * blockDim.x + threadIdx.x;
    if (tid < e) {
        unsigned long long add = (1ULL << 40)
            | (unsigned long long)__float2uint_rn(w[tid] * 1048576.0f);
        atomicAdd(&packed[col[tid]], add);
    }
    // grid-stride fp32 -> bf16 (8 elems per chunk)
    const int stride = gridDim.x * blockDim.x;
    const float4* x4 = (const float4*)x;
    for (int c = tid; c < nchunk; c += stride) {
        float4 f0 = x4[2 * c];
        float4 f1 = x4[2 * c + 1];
        bf16x8 v;
        v[0] = (short)f2bf(f0.x); v[1] = (short)f2bf(f0.y);
        v[2] = (short)f2bf(f0.z); v[3] = (short)f2bf(f0.w);
        v[4] = (short)f2bf(f1.x); v[5] = (short)f2bf(f1.y);
        v[6] = (short)f2bf(f1.z); v[7] = (short)f2bf(f1.w);
        *(bf16x8*)(xbf + (size_t)c * 8) = v;
    }
}

// ---------- pipelined bf16 GEMM: C[MP,256] = A[MP,K] @ Bt[256,K]^T ----------
// BM=BN=128, BK=32; 4 waves, 64x64 subtile each (4x4 MFMA 16x16x32).
// Register prefetch + LDS double-buffer: ONE barrier per K-step (R10-verified).
__global__ __launch_bounds__(256)
void gemm_kernel(const unsigned short* __restrict__ A,
                 const unsigned short* __restrict__ Bt,
                 unsigned short* __restrict__ C, int K) {
    __shared__ unsigned short As[2][128 * LDSTR];
    __shared__ unsigned short Bs[2][128 * LDSTR];
    const int tid  = threadIdx.x;
    const int lane = tid & 63;
    const int wv   = tid >> 6;
    const int wrow = wv >> 1, wcol = wv & 1;
    const int m0 = blockIdx.x * 128;
    const int n0 = blockIdx.y * 128;

    const int sr = tid >> 2;          // staging row 0..63
    const int sc = (tid & 3) * 8;     // staging k-offset 0,8,16,24

    const unsigned short* pa0 = A + (size_t)(m0 + sr) * K + sc;
    const unsigned short* pa1 = A + (size_t)(m0 + sr + 64) * K + sc;
    const unsigned short* pb0 = Bt + (size_t)(n0 + sr) * K + sc;
    const unsigned short* pb1 = Bt + (size_t)(n0 + sr + 64) * K + sc;

    f32x4 zero4 = {0.0f, 0.0f, 0.0f, 0.0f};
    f32x4 acc[4][4];
    #pragma unroll
    for (int i = 0; i < 4; ++i)
        #pragma unroll
        for (int j = 0; j < 4; ++j) acc[i][j] = zero4;

    const int q8 = (lane >> 4) * 8;
    const int ml = lane & 15;

    bf16x8 va0 = *(const bf16x8*)pa0;
    bf16x8 va1 = *(const bf16x8*)pa1;
    bf16x8 vb0 = *(const bf16x8*)pb0;
    bf16x8 vb1 = *(const bf16x8*)pb1;

    const int nsteps = K >> 5;
    for (int s = 0; s < nsteps; ++s) {
        const int buf = s & 1;
        *(bf16x8*)&As[buf][sr * LDSTR + sc]        = va0;
        *(bf16x8*)&As[buf][(sr + 64) * LDSTR + sc] = va1;
        *(bf16x8*)&Bs[buf][sr * LDSTR + sc]        = vb0;
        *(bf16x8*)&Bs[buf][(sr + 64) * LDSTR + sc] = vb1;
        __syncthreads();
        if (s + 1 < nsteps) {             // prefetch next tile
            int off = (s + 1) * 32;
            va0 = *(const bf16x8*)(pa0 + off);
            va1 = *(const bf16x8*)(pa1 + off);
            vb0 = *(const bf16x8*)(pb0 + off);
            vb1 = *(const bf16x8*)(pb1 + off);
        }
        bf16x8 af[4], bfr[4];
        #pragma unroll
        for (int i = 0; i < 4; ++i)
            af[i] = *(const bf16x8*)&As[buf][(wrow * 64 + i * 16 + ml) * LDSTR + q8];
        #pragma unroll
        for (int j = 0; j < 4; ++j)
            bfr[j] = *(const bf16x8*)&Bs[buf][(wcol * 64 + j * 16 + ml) * LDSTR + q8];
        #pragma unroll
        for (int i = 0; i < 4; ++i)
            #pragma unroll
            for (int j = 0; j < 4; ++j)
                acc[i][j] = __builtin_amdgcn_mfma_f32_16x16x32_bf16(af[i], bfr[j], acc[i][j], 0, 0, 0);
    }

    // C store (bf16): col=lane&15, row=(lane>>4)*4+reg
    const int q4 = (lane >> 4) * 4;
    #pragma unroll
    for (int i = 0; i < 4; ++i) {
        #pragma unroll
        for (int j = 0; j < 4; ++j) {
            #pragma unroll
            for (int rg = 0; rg < 4; ++rg) {
                int r = m0 + wrow * 64 + i * 16 + q4 + rg;
                int c = n0 + wcol * 64 + j * 16 + ml;
                C[(size_t)r * HF + c] = f2bf(acc[i][j][rg]);
            }
        }
    }
}

// ---------- scan1: block-local exclusive scan of counts ----------
__global__ void scan1_kernel(const unsigned long long* __restrict__ packed,
                             int* __restrict__ local, int* __restrict__ blocksum, int n) {
    __shared__ int tmp[SCAN_B];
    int i = blockIdx.x * SCAN_B + threadIdx.x;
    int v = (i < n) ? (int)(packed[i] >> 40) : 0;
    tmp[threadIdx.x] = v;
    __syncthreads();
    for (int off = 1; off < SCAN_B; off <<= 1) {
        int t = 0;
        if ((int)threadIdx.x >= off) t = tmp[threadIdx.x - off];
        __syncthreads();
        if ((int)threadIdx.x >= off) tmp[threadIdx.x] += t;
        __syncthreads();
    }
    if (i < n) local[i] = tmp[threadIdx.x] - v;       // exclusive
    if (threadIdx.x == SCAN_B - 1) blocksum[blockIdx.x] = tmp[SCAN_B - 1];
}

// ---------- scan3: add block prefix (re-reduced in-block) + dinv ----------
__global__ void scan3_dinv_kernel(int* __restrict__ csr_ptr, int* __restrict__ cursor,
                                  const int* __restrict__ blocksum,
                                  const unsigned long long* __restrict__ packed,
                                  float* __restrict__ dinv, int n, int e, int nb) {
    __shared__ int red[SCAN_B];
    int t = threadIdx.x;
    red[t] = (t < nb && t < (int)blockIdx.x) ? blocksum[t] : 0;
    __syncthreads();
    for (int off = SCAN_B / 2; off > 0; off >>= 1) {
        if (t < off) red[t] += red[t + off];
        __syncthreads();
    }
    int prefix = red[0];
    int i = blockIdx.x * SCAN_B + t;
    if (i < n) {
        int val = csr_ptr[i] + prefix;
        csr_ptr[i] = val;
        cursor[i] = val;
        float deg = (float)(packed[i] & 0xFFFFFFFFFFULL) * (1.0f / 1048576.0f);
        dinv[i] = rsqrtf(deg);   // deg >= 1 always (self-loop)
    }
    if (i == 0) csr_ptr[n] = e;
}

// ---------- CSR fill: bucket edges by col, fold norm, 8B paired store ----------
__global__ void fill_kernel(const int* __restrict__ row, const int* __restrict__ col,
                            const float* __restrict__ w, const float* __restrict__ dinv,
                            int* __restrict__ cursor, int2* __restrict__ csr_edge, int e) {
    int i = blockIdx.x * blockDim.x + threadIdx.x;
    if (i < e) {
        int r = row[i], c = col[i];
        int pos = atomicAdd(&cursor[c], 1);
        float nrm = dinv[r] * w[i] * dinv[c];
        csr_edge[pos] = make_int2(r, __float_as_int(nrm));
    }
}

// ---------- fused CSR gather + self-loop + bias + BN + ReLU ----------
// one wave per node; unconditional batches of 16, clamped masked tail.
// FINAL=1: additionally computes h3[node,2] = act . W3 (wave reduce), skips bf16 store.
#define AGB 16
template<int FINAL>
__global__ void agg_kernel(const unsigned short* __restrict__ h,
                           const int* __restrict__ ptr,
                           const int2* __restrict__ edge,
                           const float* __restrict__ dinv,
                           const float* __restrict__ b, const float* __restrict__ g,
                           const float* __restrict__ be, const float* __restrict__ m,
                           const float* __restrict__ v,
                           unsigned short* __restrict__ out,
                           const float* __restrict__ W3, float* __restrict__ h3, int n) {
    int wid  = (blockIdx.x * blockDim.x + threadIdx.x) >> 6;
    int lane = threadIdx.x & 63;
    if (wid >= n) return;
    int p0 = ptr[wid], p1 = ptr[wid + 1];
    const int fo = lane * 4;
    float a0 = 0.f, a1 = 0.f, a2 = 0.f, a3 = 0.f;

    const int pend = p0 + ((p1 - p0) & ~(AGB - 1));
    for (int p = p0; p < pend; p += AGB) {
        int2 ed[AGB];
        #pragma unroll
        for (int k = 0; k < AGB; ++k) ed[k] = edge[p + k];
        ushort4 hv[AGB];
        #pragma unroll
        for (int k = 0; k < AGB; ++k)
            hv[k] = *(const ushort4*)(h + (size_t)ed[k].x * HF + fo);
        #pragma unroll
        for (int k = 0; k < AGB; ++k) {
            float nw = __int_as_float(ed[k].y);
            a0 += nw * bf2f(hv[k].x);
            a1 += nw * bf2f(hv[k].y);
            a2 += nw * bf2f(hv[k].z);
            a3 += nw * bf2f(hv[k].w);
        }
    }
    if (pend < p1) {   // masked tail batch
        int2 ed[AGB];
        float wv[AGB];
        #pragma unroll
        for (int k = 0; k < AGB; ++k) {
            int idx = pend + k < p1 ? pend + k : p1 - 1;
            ed[k] = edge[idx];
            wv[k] = (pend + k < p1) ? __int_as_float(ed[k].y) : 0.0f;
        }
        ushort4 hv[AGB];
        #pragma unroll
        for (int k = 0; k < AGB; ++k)
            hv[k] = *(const ushort4*)(h + (size_t)ed[k].x * HF + fo);
        #pragma unroll
        for (int k = 0; k < AGB; ++k) {
            a0 += wv[k] * bf2f(hv[k].x);
            a1 += wv[k] * bf2f(hv[k].y);
            a2 += wv[k] * bf2f(hv[k].z);
            a3 += wv[k] * bf2f(hv[k].w);
        }
    }
    // self loop: weight 1, norm = dinv^2
    float s = dinv[wid];
    float sl = s * s;
    ushort4 hv = *(const ushort4*)(h + (size_t)wid * HF + fo);
    a0 += sl * bf2f(hv.x);
    a1 += sl * bf2f(hv.y);
    a2 += sl * bf2f(hv.z);
    a3 += sl * bf2f(hv.w);

    float4 bb  = *(const float4*)(b + fo);
    float4 gg  = *(const float4*)(g + fo);
    float4 bee = *(const float4*)(be + fo);
    float4 mm  = *(const float4*)(m + fo);
    float4 vv  = *(const float4*)(v + fo);
    float f0 = fmaxf((a0 + bb.x - mm.x) * rsqrtf(vv.x + BN_EPS) * gg.x + bee.x, 0.f);
    float f1 = fmaxf((a1 + bb.y - mm.y) * rsqrtf(vv.y + BN_EPS) * gg.y + bee.y, 0.f);
    float f2 = fmaxf((a2 + bb.z - mm.z) * rsqrtf(vv.z + BN_EPS) * gg.z + bee.z, 0.f);
    float f3 = fmaxf((a3 + bb.w - mm.w) * rsqrtf(vv.w + BN_EPS) * gg.w + bee.w, 0.f);

    if (!FINAL) {
        ushort4 o;
        o.x = f2bf(f0); o.y = f2bf(f1); o.z = f2bf(f2); o.w = f2bf(f3);
        *(ushort4*)(out + (size_t)wid * HF + fo) = o;
    } else {
        // fused layer-3 GEMV: h3[wid, o] = sum_f act[f] * W3[f][o]
        float4 w0 = *(const float4*)(W3 + fo * 2);
        float4 w1 = *(const float4*)(W3 + fo * 2 + 4);
        float s0 = f0 * w0.x + f1 * w0.z + f2 * w1.x + f3 * w1.z;
        float s1 = f0 * w0.y + f1 * w0.w + f2 * w1.y + f3 * w1.w;
        #pragma unroll
        for (int o = 32; o > 0; o >>= 1) {
            s0 += __shfl_down(s0, o, 64);
            s1 += __shfl_down(s1, o, 64);
        }
        if (lane == 0) {
            h3[wid * 2 + 0] = s0;
            h3[wid * 2 + 1] = s1;
        }
    }
}

// ---------- final: CSR gather (2 features) + self-loop + bias ----------
__global__ void out_kernel(const float* __restrict__ h3,
                           const int* __restrict__ ptr, const int2* __restrict__ edge,
                           const float* __restrict__ dinv,
                           const float* __restrict__ b3, float* __restrict__ out, int n) {
    int i = blockIdx.x * blockDim.x + threadIdx.x;
    if (i >= n) return;
    int p0 = ptr[i], p1 = ptr[i + 1];
    float a0 = 0.f, a1 = 0.f;
    for (int p = p0; p < p1; p += 4) {
        #pragma unroll
        for (int k = 0; k < 4; ++k) {
            int idx = p + k < p1 ? p + k : p1 - 1;
            int2 e = edge[idx];
            float nw = (p + k < p1) ? __int_as_float(e.y) : 0.0f;
            float2 u = *(const float2*)(h3 + 2 * e.x);
            a0 += nw * u.x;
            a1 += nw * u.y;
        }
    }
    float s = dinv[i];
    float sl = s * s;
    out[2 * i + 0] = a0 + sl * h3[2 * i + 0] + b3[0];
    out[2 * i + 1] = a1 + sl * h3[2 * i + 1] + b3[1];
}

static inline char* align16(char* p) {
    return (char*)(((uintptr_t)p + 15) & ~(uintptr_t)15);
}

extern "C" void kernel_launch(void* const* d_in, const int* in_sizes, int n_in,
                              void* d_out, int out_size, void* d_ws, size_t ws_size,
                              hipStream_t stream) {
    const float* x   = (const float*)d_in[0];
    const int*   ei  = (const int*)d_in[1];    // int64 in reference -> int32 in harness
    const float* ew  = (const float*)d_in[2];
    const float* W1  = (const float*)d_in[3];
    const float* b1  = (const float*)d_in[4];
    const float* g1  = (const float*)d_in[5];
    const float* be1 = (const float*)d_in[6];
    const float* m1  = (const float*)d_in[7];
    const float* v1  = (const float*)d_in[8];
    const float* W2  = (const float*)d_in[9];
    const float* b2  = (const float*)d_in[10];
    const float* g2  = (const float*)d_in[11];
    const float* be2 = (const float*)d_in[12];
    const float* m2  = (const float*)d_in[13];
    const float* v2  = (const float*)d_in[14];
    const float* W3  = (const float*)d_in[15];
    const float* b3  = (const float*)d_in[16];

    const int N  = in_sizes[0] / F_IN;         // 50000
    const int E  = in_sizes[2];                // 800000
    const int MP = (N + 127) & ~127;           // 50048
    const int* row = ei;
    const int* col = ei + E;

    char* wsb = (char*)d_ws;
    unsigned long long* packed = (unsigned long long*)wsb; wsb = align16(wsb + (size_t)N * 8);
    float* dinv     = (float*)wsb;          wsb = align16(wsb + (size_t)N * 4);
    int*   csr_ptr  = (int*)wsb;            wsb = align16(wsb + (size_t)(N + 1) * 4);
    int*   cursor   = (int*)wsb;            wsb = align16(wsb + (size_t)N * 4);
    int*   blocksum = (int*)wsb;            wsb = align16(wsb + (size_t)SCAN_B * 4);
    int2*  csr_edge = (int2*)wsb;           wsb = align16(wsb + (size_t)E * 8);
    unsigned short* W1t = (unsigned short*)wsb;  wsb = align16(wsb + (size_t)F_IN * HF * 2);
    unsigned short* W2t = (unsigned short*)wsb;  wsb = align16(wsb + (size_t)HF * HF * 2);
    unsigned short* xbf  = (unsigned short*)wsb; wsb = align16(wsb + (size_t)MP * F_IN * 2);
    unsigned short* bufh = (unsigned short*)wsb; wsb = align16(wsb + (size_t)MP * HF * 2);
    unsigned short* bufa = (unsigned short*)wsb; wsb = align16(wsb + (size_t)MP * HF * 2);
    float* h3 = (float*)wsb;                wsb = align16(wsb + (size_t)N * OUT_F * 4);
    float* outf = (float*)d_out;

    const int TB = 256;
    const int nscan = (N + SCAN_B - 1) / SCAN_B;        // 196
    const int padx = (MP - N) * F_IN;
    const int pada = (MP - N) * HF;
    const int preptot = N + F_IN * HF + HF * HF + padx + pada;
    const int ncc = (E + TB - 1) / TB;                  // 3125 blocks: 1 edge/thread
    const int nchunk = (N * F_IN) / 8;                  // 3.2M bf16x8 chunks

    // --- prep: packed init + weight transposes + pad zeroing ---
    prep_kernel<<<(preptot + TB - 1) / TB, TB, 0, stream>>>(
        packed, W1, W1t, W2, W2t, xbf + (size_t)N * F_IN, bufa + (size_t)N * HF, N, padx, pada);

    // --- count atomics (1 edge/thread) + x->bf16 conversion (grid-stride) ---
    count_conv_kernel<<<ncc, TB, 0, stream>>>(col, ew, packed, x, xbf, E, nchunk);

    // --- CSR build ---
    scan1_kernel<<<nscan, SCAN_B, 0, stream>>>(packed, csr_ptr, blocksum, N);
    scan3_dinv_kernel<<<nscan, SCAN_B, 0, stream>>>(csr_ptr, cursor, blocksum, packed, dinv, N, E, nscan);
    fill_kernel<<<(E + TB - 1) / TB, TB, 0, stream>>>(row, col, ew, dinv, cursor, csr_edge, E);

    dim3 ggrid(MP / 128, HF / 128);   // (391, 2)

    // --- layer 1 ---
    gemm_kernel<<<ggrid, TB, 0, stream>>>(xbf, W1t, bufh, F_IN);
    agg_kernel<0><<<((size_t)N * 64 + TB - 1) / TB, TB, 0, stream>>>(
        bufh, csr_ptr, csr_edge, dinv, b1, g1, be1, m1, v1, bufa, nullptr, nullptr, N);

    // --- layer 2 ---
    gemm_kernel<<<ggrid, TB, 0, stream>>>(bufa, W2t, bufh, HF);
    agg_kernel<1><<<((size_t)N * 64 + TB - 1) / TB, TB, 0, stream>>>(
        bufh, csr_ptr, csr_edge, dinv, b2, g2, be2, m2, v2, nullptr, W3, h3, N);

    // --- final 2-feature aggregation ---
    out_kernel<<<(N + TB - 1) / TB, TB, 0, stream>>>(h3, csr_ptr, csr_edge, dinv, b3, outf, N);
}